// Round 2
// baseline (796.067 us; speedup 1.0000x reference)
//
#include <hip/hip_runtime.h>

// GRU teacher-forced NLL, B=8192, S=2048, H=8, IN_DIM=4, NCLS=10.
// R18: occupancy 2x. R17 calibration showed VALUBusy is SIMD-16-formula
// inflated (true ~41%) -> latency-bound on the per-step serial chain
// (MFMA -> 5-deep trans chain -> swap -> MFMA), hidden by only 4 waves/SIMD.
// Split into 32 chunks x 64 steps -> 2048 blocks = 8 blocks/CU = 32 waves/CU
// (HW max), launch_bounds(256,8) caps VGPR at 64 (R17 used 52).
// Also: B-fragment build cut from 6 cndmask to 2 — dot2s take (own,other)
// order with per-lane-permuted class-8/9 weights (dot is order-invariant);
// k12-15 garbage multiplies zero A-columns.
//
// MFMA layout (v_mfma_f32_32x32x16_f16, one per step):
//   rows 0-7  = r-gate   (S1 * [Whr | Wir]),  bias S1*(bir+bhr) via C
//   rows 8-15 = z-gate   (S1 * [Whz | Wiz]),  bias S1*(biz+bhz) via C
//   rows 16-23= n h-part (2S1 * [Whn | 0 ]),  bias 2S1*bhn      via C
//   rows 24-31= logits 0-7 (S1 * [Wout | 0]), bias S1*bout      via C
//   K: k0-7 = h (f16), k8-11 = x bits, k12-15 = 0. cols = 32 batch elems.

#define SEQ    2048
#define BATCH  8192
#define WARM   16
#define CLEN   64
#define NCHUNK 32

using hh2    = decltype(__builtin_amdgcn_cvt_pkrtz(0.0f, 0.0f));
using f16x8  = __attribute__((ext_vector_type(8))) _Float16;
using f32x16 = __attribute__((ext_vector_type(16))) float;
using i32x4  = __attribute__((ext_vector_type(4))) int;

#if defined(__has_builtin)
# if __has_builtin(__builtin_amdgcn_permlane32_swap)
#  define HAVE_PLS 1
# endif
#endif
#ifndef HAVE_PLS
# define HAVE_PLS 0
#endif

static __device__ __forceinline__ float dot2(hh2 a, hh2 b, float c) {
    return __builtin_amdgcn_fdot2(a, b, c, false);
}

struct BTrue  { static constexpr bool value = true;  };
struct BFalse { static constexpr bool value = false; };

__global__ __launch_bounds__(256, 8)
void gru_nll_kernel(const int* __restrict__ xb,
                    const float* __restrict__ Wir, const float* __restrict__ bir,
                    const float* __restrict__ Wiz, const float* __restrict__ biz,
                    const float* __restrict__ Win, const float* __restrict__ bin_,
                    const float* __restrict__ Whr, const float* __restrict__ bhr,
                    const float* __restrict__ Whz, const float* __restrict__ bhz,
                    const float* __restrict__ Whn, const float* __restrict__ bhn,
                    const float* __restrict__ Wout, const float* __restrict__ bout,
                    float* __restrict__ out)
{
    constexpr float S1 = 1.4426950408889634f;   // log2(e)
    __shared__ float4 tblg[10][2];   // [count][half] = 2*S1*(Win·x + bin) comps 4h..4h+3
    __shared__ float2 tblx[10];      // [count] = packed f16 x-bits {x0,x1},{x2,x3}
    __shared__ float  red[256];

    const int tid = threadIdx.x;

    if (tid < 20) {
        int c = tid >> 1, h2 = tid & 1;
        float b0 = (float)((c >> 3) & 1);
        float b1 = (float)((c >> 2) & 1);
        float b2 = (float)((c >> 1) & 1);
        float b3 = (float)(c & 1);
        float4 v;
        float* vp = (float*)&v;
        #pragma unroll
        for (int j = 0; j < 4; ++j) {
            int ii = h2 * 4 + j;
            float gn = bin_[ii] + b0*Win[ii*4+0] + b1*Win[ii*4+1]
                                + b2*Win[ii*4+2] + b3*Win[ii*4+3];
            vp[j] = 2.0f * S1 * gn;
        }
        tblg[c][h2] = v;
        if (h2 == 0) {
            hh2 plo = __builtin_amdgcn_cvt_pkrtz(b0, b1);
            hh2 phi = __builtin_amdgcn_cvt_pkrtz(b2, b3);
            tblx[c] = make_float2(__builtin_bit_cast(float, plo),
                                  __builtin_bit_cast(float, phi));
        }
    }
    __syncthreads();

    const int wid  = tid >> 6;
    const int lane = tid & 63;
    const int col  = lane & 31;          // batch sub-index within wave
    const int hi   = lane >> 5;          // 0: comps 0-3 / k0-7, 1: comps 4-7 / k8-15
    const bool lo  = (hi == 0);

    const int chunk = blockIdx.x & (NCHUNK - 1);           // block-uniform
    const int b     = (blockIdx.x >> 5) * 128 + wid * 32 + col;

    // ---- A fragment: row = lane&31, k = 8*hi + e (consecutive f16 = consecutive k)
    const int row = lane & 31;
    const int g   = row >> 3;
    const int rr_ = row & 7;
    f16x8 af;
    #pragma unroll
    for (int e = 0; e < 8; ++e) {
        int k = hi * 8 + e;
        float w = 0.0f;
        if (k < 8) {
            if      (g == 0) w = S1       * Whr[rr_*8 + k];
            else if (g == 1) w = S1       * Whz[rr_*8 + k];
            else if (g == 2) w = 2.0f*S1  * Whn[rr_*8 + k];
            else             w = S1       * Wout[rr_*8 + k];
        } else if (k < 12) {
            int xi = k - 8;
            if      (g == 0) w = S1 * Wir[rr_*4 + xi];
            else if (g == 1) w = S1 * Wiz[rr_*4 + xi];
        }
        af[e] = (_Float16)w;
    }

    // ---- C bias: col=lane&31, row(reg) = (reg&3) + 8*(reg>>2) + 4*hi
    f32x16 cb;
    #pragma unroll
    for (int r2 = 0; r2 < 16; ++r2) {
        int rw = (r2 & 3) + 8 * (r2 >> 2) + 4 * hi;
        int gg = rw >> 3, cp = rw & 7;
        float v;
        if      (gg == 0) v = S1 * (bir[cp] + bhr[cp]);
        else if (gg == 1) v = S1 * (biz[cp] + bhz[cp]);
        else if (gg == 2) v = 2.0f * S1 * bhn[cp];
        else              v = S1 * bout[(r2 & 3) + 4 * hi];
        cb[r2] = v;
    }

    // ---- class 8/9 weights, permuted to this lane's (own, other) comp order
    const int cls89 = 8 + hi;
    const int cls0  = 4 * hi;
    hh2 wc89[4];
    #pragma unroll
    for (int q = 0; q < 4; ++q) {
        int base_ = ((q < 2) ? 4 * hi : 4 * (1 - hi)) + (q & 1) * 2;
        wc89[q] = __builtin_amdgcn_cvt_pkrtz(S1 * Wout[cls89*8 + base_],
                                             S1 * Wout[cls89*8 + base_ + 1]);
    }
    const float b89 = S1 * bout[cls89];

    // ---- lane<->lane^32 exchange, semantics-robust
#if HAVE_PLS
    bool useR1;
    {
        unsigned probe = lo ? 0u : 1u;
        unsigned want  = 1u - probe;
        auto rr = __builtin_amdgcn_permlane32_swap(probe, probe, false, false);
        useR1 = (rr[1] == want);
    }
    auto oth = [&](int v) -> int {
        auto rr = __builtin_amdgcn_permlane32_swap((unsigned)v, (unsigned)v, false, false);
        return useR1 ? (int)rr[1] : (int)rr[0];
    };
#else
    auto oth = [&](int v) -> int { return __shfl_xor(v, 32, 64); };
#endif

    // ---- count stream: iter t consumes cnt = x[t-1]; losses for t>=chunk*CLEN+1
    const int* base   = xb + (size_t)b * SEQ;
    const int  tstart = chunk * CLEN - (chunk ? WARM : 0);
    const int  cinit  = chunk ? base[tstart - 1] : 0;
    const int4* p4    = (const int4*)(base + tstart);
    const int  wb     = chunk ? (WARM / 4) : 0;   // warm int4-blocks
    const int  nb     = wb + CLEN / 4;            // total int4-blocks

    const float4* tg = &tblg[0][hi];              // tg[2*cnt] = tblg[cnt][hi]

    int    cnt = cinit;
    float4 gz4 = tg[cnt * 2];
    float2 xB  = tblx[cnt];
    int xw0 = __builtin_bit_cast(int, xB.x);
    int xw1 = __builtin_bit_cast(int, xB.y);

    float hp0 = 0.f, hp1 = 0.f, hp2 = 0.f, hp3 = 0.f;   // own comps, exact f32
    int own01 = 0, own23 = 0;                            // packed f16 of own comps
    float accp = 0.f, acct = 0.f, P = 1.f;

    auto step = [&](int cnext, auto lossc) {
        constexpr bool LOSS = decltype(lossc)::value;
        // partner's packed h comps; B fragment in (own, other) order.
        // lo lane supplies k0-7 = h0..h7 = (own01,own23,o01,o23) — canonical.
        // hi lane supplies k8-11 = x bits; k12-15 hit zero A columns (garbage ok).
        int o01 = oth(own01), o23 = oth(own23);
        int bb0 = lo ? own01 : xw0;
        int bb1 = lo ? own23 : xw1;
        i32x4 bw = {bb0, bb1, o01, o23};
        f16x8 bf = __builtin_bit_cast(f16x8, bw);
        f32x16 d = __builtin_amdgcn_mfma_f32_32x32x16_f16(af, bf, cb, 0, 0, 0);

        // prefetch next-iter tables (latency hidden under gate math)
        float4 gzn = tg[cnext * 2];
        float2 xbn = tblx[cnext];

        float l89;
        if constexpr (LOSS) {
            // dot in (own, other) order; wc89 was permuted to match this lane
            l89 = b89;
            l89 = dot2(__builtin_bit_cast(hh2, own01), wc89[0], l89);
            l89 = dot2(__builtin_bit_cast(hh2, own23), wc89[1], l89);
            l89 = dot2(__builtin_bit_cast(hh2, o01),   wc89[2], l89);
            l89 = dot2(__builtin_bit_cast(hh2, o23),   wc89[3], l89);
        }

        // gates / h update for this lane's 4 comps
        float gza[4] = {gz4.x, gz4.y, gz4.z, gz4.w};
        float hpa[4] = {hp0, hp1, hp2, hp3};
        float hnv[4];
        #pragma unroll
        for (int j = 0; j < 4; ++j) {
            float ar = d[j], az = d[4 + j], hn = d[8 + j];
            float er = __builtin_amdgcn_exp2f(-ar);
            float ez = __builtin_amdgcn_exp2f(-az);
            float ir = __builtin_amdgcn_rcpf(1.0f + er);
            float u  = __builtin_fmaf(hn, ir, gza[j]);
            float E  = __builtin_amdgcn_exp2f(u);
            float a_ = E + 1.0f;
            float c_ = E - 1.0f;
            float m_ = ez * c_;
            float num = __builtin_fmaf(hpa[j], a_, m_);
            float den = a_ * (1.0f + ez);
            hnv[j] = num * __builtin_amdgcn_rcpf(den);
        }
        hp0 = hnv[0]; hp1 = hnv[1]; hp2 = hnv[2]; hp3 = hnv[3];
        own01 = __builtin_bit_cast(int, __builtin_amdgcn_cvt_pkrtz(hnv[0], hnv[1]));
        own23 = __builtin_bit_cast(int, __builtin_amdgcn_cvt_pkrtz(hnv[2], hnv[3]));

        // softmax/NLL of lagged logits (rows 24-31 of same mfma = logits(h(t-1)))
        if constexpr (LOSS) {
            float l0 = d[12], l1 = d[13], l2 = d[14], l3 = d[15];
            float e0 = __builtin_amdgcn_exp2f(l0);
            float e1 = __builtin_amdgcn_exp2f(l1);
            float e2 = __builtin_amdgcn_exp2f(l2);
            float e3 = __builtin_amdgcn_exp2f(l3);
            float e8 = __builtin_amdgcn_exp2f(l89);
            float so = ((e0 + e1) + (e2 + e3)) + e8;
            float st = so + __builtin_bit_cast(float, oth(__builtin_bit_cast(int, so)));
            P *= st;                       // identical bits on both pair lanes
            float sel = 0.0f;              // target = cnt (= x[t-1], loss step t-1)
            sel = (cnt == cls0 + 0) ? l0  : sel;
            sel = (cnt == cls0 + 1) ? l1  : sel;
            sel = (cnt == cls0 + 2) ? l2  : sel;
            sel = (cnt == cls0 + 3) ? l3  : sel;
            sel = (cnt == cls89   ) ? l89 : sel;
            acct += sel;                   // exactly one lane of the pair matches
        }
        cnt = cnext;
        gz4 = gzn;
        xw0 = __builtin_bit_cast(int, xbn.x);
        xw1 = __builtin_bit_cast(int, xbn.y);
    };

    int4 cc = p4[0];
    step(cc.x, BFalse{});                          // iter0: current = cinit
    for (int jb = 0; jb < wb; ++jb) {              // warm: 16 streamed iters
        int4 nx = p4[jb + 1];
        step(cc.y, BFalse{}); step(cc.z, BFalse{});
        step(cc.w, BFalse{}); step(nx.x, BFalse{});
        cc = nx;
    }
    for (int jb = wb; jb < nb; ++jb) {             // main: CLEN loss iters
        int4 nx = p4[(jb + 1 < nb) ? (jb + 1) : 0];
        step(cc.y, BTrue{}); step(cc.z, BTrue{});
        step(cc.w, BTrue{}); step(nx.x, BTrue{});
        cc = nx;
        if ((jb - wb) & 1) { accp += __builtin_amdgcn_logf(P); P = 1.0f; }  // log2
    }

    // accp is duplicated across the lane pair -> x0.5; acct is not.
    red[tid] = __builtin_fmaf(accp, 0.5f, -acct);
    __syncthreads();
    #pragma unroll
    for (int sft = 128; sft > 0; sft >>= 1) {
        if (tid < sft) red[tid] += red[tid + sft];
        __syncthreads();
    }
    if (tid == 0) {
        constexpr float SCALE =
            (float)(0.69314718055994530942 / (8192.0 * 2048.0));
        atomicAdd(out, red[0] * SCALE);
    }
}

extern "C" void kernel_launch(void* const* d_in, const int* in_sizes, int n_in,
                              void* d_out, int out_size, void* d_ws, size_t ws_size,
                              hipStream_t stream) {
    (void)hipMemsetAsync(d_out, 0, sizeof(float), stream);
    // 64 batch-groups (128 elems: 4 waves x 32) x 32 chunks = 2048 blocks
    // = 8 blocks/CU = 32 waves/CU (HW max) at <=64 VGPR.
    gru_nll_kernel<<<2048, 256, 0, stream>>>(
        (const int*)d_in[0],
        (const float*)d_in[1],  (const float*)d_in[2],
        (const float*)d_in[3],  (const float*)d_in[4],
        (const float*)d_in[5],  (const float*)d_in[6],
        (const float*)d_in[7],  (const float*)d_in[8],
        (const float*)d_in[9],  (const float*)d_in[10],
        (const float*)d_in[11], (const float*)d_in[12],
        (const float*)d_in[13], (const float*)d_in[14],
        (float*)d_out);
}

// Round 3
// 241.410 us; speedup vs baseline: 3.2976x; 3.2976x over previous
//
#include <hip/hip_runtime.h>

// GRU teacher-forced NLL, B=8192, S=2048, H=8, IN_DIM=4, NCLS=10.
// R19: R18 post-mortem — __launch_bounds__(256,8) forced the allocator to
// ~32 arch VGPRs (MFMA acc + C-bias share the unified file) -> full scratch
// spill: WRITE_SIZE 32KB -> 1.1GB, 4.4x regression. The occupancy goal never
// needed the bound: R17 compiled to 52 VGPR under (256,4), and 52 <= 64
// already permits 8 waves/SIMD at runtime (m69 occupancy steps at 64/128/256).
// R19 = 32-chunk grid (2048 blocks = 8 blocks/CU = 32 waves/CU launched)
// + the spill-free (256,4) bound. Step body identical to R18.
//
// MFMA layout (v_mfma_f32_32x32x16_f16, one per step):
//   rows 0-7  = r-gate   (S1 * [Whr | Wir]),  bias S1*(bir+bhr) via C
//   rows 8-15 = z-gate   (S1 * [Whz | Wiz]),  bias S1*(biz+bhz) via C
//   rows 16-23= n h-part (2S1 * [Whn | 0 ]),  bias 2S1*bhn      via C
//   rows 24-31= logits 0-7 (S1 * [Wout | 0]), bias S1*bout      via C
//   K: k0-7 = h (f16), k8-11 = x bits, k12-15 = 0. cols = 32 batch elems.

#define SEQ    2048
#define BATCH  8192
#define WARM   16
#define CLEN   64
#define NCHUNK 32

using hh2    = decltype(__builtin_amdgcn_cvt_pkrtz(0.0f, 0.0f));
using f16x8  = __attribute__((ext_vector_type(8))) _Float16;
using f32x16 = __attribute__((ext_vector_type(16))) float;
using i32x4  = __attribute__((ext_vector_type(4))) int;

#if defined(__has_builtin)
# if __has_builtin(__builtin_amdgcn_permlane32_swap)
#  define HAVE_PLS 1
# endif
#endif
#ifndef HAVE_PLS
# define HAVE_PLS 0
#endif

static __device__ __forceinline__ float dot2(hh2 a, hh2 b, float c) {
    return __builtin_amdgcn_fdot2(a, b, c, false);
}

struct BTrue  { static constexpr bool value = true;  };
struct BFalse { static constexpr bool value = false; };

__global__ __launch_bounds__(256, 4)
void gru_nll_kernel(const int* __restrict__ xb,
                    const float* __restrict__ Wir, const float* __restrict__ bir,
                    const float* __restrict__ Wiz, const float* __restrict__ biz,
                    const float* __restrict__ Win, const float* __restrict__ bin_,
                    const float* __restrict__ Whr, const float* __restrict__ bhr,
                    const float* __restrict__ Whz, const float* __restrict__ bhz,
                    const float* __restrict__ Whn, const float* __restrict__ bhn,
                    const float* __restrict__ Wout, const float* __restrict__ bout,
                    float* __restrict__ out)
{
    constexpr float S1 = 1.4426950408889634f;   // log2(e)
    __shared__ float4 tblg[10][2];   // [count][half] = 2*S1*(Win·x + bin) comps 4h..4h+3
    __shared__ float2 tblx[10];      // [count] = packed f16 x-bits {x0,x1},{x2,x3}
    __shared__ float  red[256];

    const int tid = threadIdx.x;

    if (tid < 20) {
        int c = tid >> 1, h2 = tid & 1;
        float b0 = (float)((c >> 3) & 1);
        float b1 = (float)((c >> 2) & 1);
        float b2 = (float)((c >> 1) & 1);
        float b3 = (float)(c & 1);
        float4 v;
        float* vp = (float*)&v;
        #pragma unroll
        for (int j = 0; j < 4; ++j) {
            int ii = h2 * 4 + j;
            float gn = bin_[ii] + b0*Win[ii*4+0] + b1*Win[ii*4+1]
                                + b2*Win[ii*4+2] + b3*Win[ii*4+3];
            vp[j] = 2.0f * S1 * gn;
        }
        tblg[c][h2] = v;
        if (h2 == 0) {
            hh2 plo = __builtin_amdgcn_cvt_pkrtz(b0, b1);
            hh2 phi = __builtin_amdgcn_cvt_pkrtz(b2, b3);
            tblx[c] = make_float2(__builtin_bit_cast(float, plo),
                                  __builtin_bit_cast(float, phi));
        }
    }
    __syncthreads();

    const int wid  = tid >> 6;
    const int lane = tid & 63;
    const int col  = lane & 31;          // batch sub-index within wave
    const int hi   = lane >> 5;          // 0: comps 0-3 / k0-7, 1: comps 4-7 / k8-15
    const bool lo  = (hi == 0);

    const int chunk = blockIdx.x & (NCHUNK - 1);           // block-uniform
    const int b     = (blockIdx.x >> 5) * 128 + wid * 32 + col;

    // ---- A fragment: row = lane&31, k = 8*hi + e (consecutive f16 = consecutive k)
    const int row = lane & 31;
    const int g   = row >> 3;
    const int rr_ = row & 7;
    f16x8 af;
    #pragma unroll
    for (int e = 0; e < 8; ++e) {
        int k = hi * 8 + e;
        float w = 0.0f;
        if (k < 8) {
            if      (g == 0) w = S1       * Whr[rr_*8 + k];
            else if (g == 1) w = S1       * Whz[rr_*8 + k];
            else if (g == 2) w = 2.0f*S1  * Whn[rr_*8 + k];
            else             w = S1       * Wout[rr_*8 + k];
        } else if (k < 12) {
            int xi = k - 8;
            if      (g == 0) w = S1 * Wir[rr_*4 + xi];
            else if (g == 1) w = S1 * Wiz[rr_*4 + xi];
        }
        af[e] = (_Float16)w;
    }

    // ---- C bias: col=lane&31, row(reg) = (reg&3) + 8*(reg>>2) + 4*hi
    f32x16 cb;
    #pragma unroll
    for (int r2 = 0; r2 < 16; ++r2) {
        int rw = (r2 & 3) + 8 * (r2 >> 2) + 4 * hi;
        int gg = rw >> 3, cp = rw & 7;
        float v;
        if      (gg == 0) v = S1 * (bir[cp] + bhr[cp]);
        else if (gg == 1) v = S1 * (biz[cp] + bhz[cp]);
        else if (gg == 2) v = 2.0f * S1 * bhn[cp];
        else              v = S1 * bout[(r2 & 3) + 4 * hi];
        cb[r2] = v;
    }

    // ---- class 8/9 weights, permuted to this lane's (own, other) comp order
    const int cls89 = 8 + hi;
    const int cls0  = 4 * hi;
    hh2 wc89[4];
    #pragma unroll
    for (int q = 0; q < 4; ++q) {
        int base_ = ((q < 2) ? 4 * hi : 4 * (1 - hi)) + (q & 1) * 2;
        wc89[q] = __builtin_amdgcn_cvt_pkrtz(S1 * Wout[cls89*8 + base_],
                                             S1 * Wout[cls89*8 + base_ + 1]);
    }
    const float b89 = S1 * bout[cls89];

    // ---- lane<->lane^32 exchange, semantics-robust
#if HAVE_PLS
    bool useR1;
    {
        unsigned probe = lo ? 0u : 1u;
        unsigned want  = 1u - probe;
        auto rr = __builtin_amdgcn_permlane32_swap(probe, probe, false, false);
        useR1 = (rr[1] == want);
    }
    auto oth = [&](int v) -> int {
        auto rr = __builtin_amdgcn_permlane32_swap((unsigned)v, (unsigned)v, false, false);
        return useR1 ? (int)rr[1] : (int)rr[0];
    };
#else
    auto oth = [&](int v) -> int { return __shfl_xor(v, 32, 64); };
#endif

    // ---- count stream: iter t consumes cnt = x[t-1]; losses for t>=chunk*CLEN+1
    const int* base   = xb + (size_t)b * SEQ;
    const int  tstart = chunk * CLEN - (chunk ? WARM : 0);
    const int  cinit  = chunk ? base[tstart - 1] : 0;
    const int4* p4    = (const int4*)(base + tstart);
    const int  wb     = chunk ? (WARM / 4) : 0;   // warm int4-blocks
    const int  nb     = wb + CLEN / 4;            // total int4-blocks

    const float4* tg = &tblg[0][hi];              // tg[2*cnt] = tblg[cnt][hi]

    int    cnt = cinit;
    float4 gz4 = tg[cnt * 2];
    float2 xB  = tblx[cnt];
    int xw0 = __builtin_bit_cast(int, xB.x);
    int xw1 = __builtin_bit_cast(int, xB.y);

    float hp0 = 0.f, hp1 = 0.f, hp2 = 0.f, hp3 = 0.f;   // own comps, exact f32
    int own01 = 0, own23 = 0;                            // packed f16 of own comps
    float accp = 0.f, acct = 0.f, P = 1.f;

    auto step = [&](int cnext, auto lossc) {
        constexpr bool LOSS = decltype(lossc)::value;
        // partner's packed h comps; B fragment in (own, other) order.
        // lo lane supplies k0-7 = h0..h7 = (own01,own23,o01,o23) — canonical.
        // hi lane supplies k8-11 = x bits; k12-15 hit zero A columns (garbage ok).
        int o01 = oth(own01), o23 = oth(own23);
        int bb0 = lo ? own01 : xw0;
        int bb1 = lo ? own23 : xw1;
        i32x4 bw = {bb0, bb1, o01, o23};
        f16x8 bf = __builtin_bit_cast(f16x8, bw);
        f32x16 d = __builtin_amdgcn_mfma_f32_32x32x16_f16(af, bf, cb, 0, 0, 0);

        // prefetch next-iter tables (latency hidden under gate math)
        float4 gzn = tg[cnext * 2];
        float2 xbn = tblx[cnext];

        float l89;
        if constexpr (LOSS) {
            // dot in (own, other) order; wc89 was permuted to match this lane
            l89 = b89;
            l89 = dot2(__builtin_bit_cast(hh2, own01), wc89[0], l89);
            l89 = dot2(__builtin_bit_cast(hh2, own23), wc89[1], l89);
            l89 = dot2(__builtin_bit_cast(hh2, o01),   wc89[2], l89);
            l89 = dot2(__builtin_bit_cast(hh2, o23),   wc89[3], l89);
        }

        // gates / h update for this lane's 4 comps
        float gza[4] = {gz4.x, gz4.y, gz4.z, gz4.w};
        float hpa[4] = {hp0, hp1, hp2, hp3};
        float hnv[4];
        #pragma unroll
        for (int j = 0; j < 4; ++j) {
            float ar = d[j], az = d[4 + j], hn = d[8 + j];
            float er = __builtin_amdgcn_exp2f(-ar);
            float ez = __builtin_amdgcn_exp2f(-az);
            float ir = __builtin_amdgcn_rcpf(1.0f + er);
            float u  = __builtin_fmaf(hn, ir, gza[j]);
            float E  = __builtin_amdgcn_exp2f(u);
            float a_ = E + 1.0f;
            float c_ = E - 1.0f;
            float m_ = ez * c_;
            float num = __builtin_fmaf(hpa[j], a_, m_);
            float den = a_ * (1.0f + ez);
            hnv[j] = num * __builtin_amdgcn_rcpf(den);
        }
        hp0 = hnv[0]; hp1 = hnv[1]; hp2 = hnv[2]; hp3 = hnv[3];
        own01 = __builtin_bit_cast(int, __builtin_amdgcn_cvt_pkrtz(hnv[0], hnv[1]));
        own23 = __builtin_bit_cast(int, __builtin_amdgcn_cvt_pkrtz(hnv[2], hnv[3]));

        // softmax/NLL of lagged logits (rows 24-31 of same mfma = logits(h(t-1)))
        if constexpr (LOSS) {
            float l0 = d[12], l1 = d[13], l2 = d[14], l3 = d[15];
            float e0 = __builtin_amdgcn_exp2f(l0);
            float e1 = __builtin_amdgcn_exp2f(l1);
            float e2 = __builtin_amdgcn_exp2f(l2);
            float e3 = __builtin_amdgcn_exp2f(l3);
            float e8 = __builtin_amdgcn_exp2f(l89);
            float so = ((e0 + e1) + (e2 + e3)) + e8;
            float st = so + __builtin_bit_cast(float, oth(__builtin_bit_cast(int, so)));
            P *= st;                       // identical bits on both pair lanes
            float sel = 0.0f;              // target = cnt (= x[t-1], loss step t-1)
            sel = (cnt == cls0 + 0) ? l0  : sel;
            sel = (cnt == cls0 + 1) ? l1  : sel;
            sel = (cnt == cls0 + 2) ? l2  : sel;
            sel = (cnt == cls0 + 3) ? l3  : sel;
            sel = (cnt == cls89   ) ? l89 : sel;
            acct += sel;                   // exactly one lane of the pair matches
        }
        cnt = cnext;
        gz4 = gzn;
        xw0 = __builtin_bit_cast(int, xbn.x);
        xw1 = __builtin_bit_cast(int, xbn.y);
    };

    int4 cc = p4[0];
    step(cc.x, BFalse{});                          // iter0: current = cinit
    for (int jb = 0; jb < wb; ++jb) {              // warm: 16 streamed iters
        int4 nx = p4[jb + 1];
        step(cc.y, BFalse{}); step(cc.z, BFalse{});
        step(cc.w, BFalse{}); step(nx.x, BFalse{});
        cc = nx;
    }
    for (int jb = wb; jb < nb; ++jb) {             // main: CLEN loss iters
        int4 nx = p4[(jb + 1 < nb) ? (jb + 1) : 0];
        step(cc.y, BTrue{}); step(cc.z, BTrue{});
        step(cc.w, BTrue{}); step(nx.x, BTrue{});
        cc = nx;
        if ((jb - wb) & 1) { accp += __builtin_amdgcn_logf(P); P = 1.0f; }  // log2
    }

    // accp is duplicated across the lane pair -> x0.5; acct is not.
    red[tid] = __builtin_fmaf(accp, 0.5f, -acct);
    __syncthreads();
    #pragma unroll
    for (int sft = 128; sft > 0; sft >>= 1) {
        if (tid < sft) red[tid] += red[tid + sft];
        __syncthreads();
    }
    if (tid == 0) {
        constexpr float SCALE =
            (float)(0.69314718055994530942 / (8192.0 * 2048.0));
        atomicAdd(out, red[0] * SCALE);
    }
}

extern "C" void kernel_launch(void* const* d_in, const int* in_sizes, int n_in,
                              void* d_out, int out_size, void* d_ws, size_t ws_size,
                              hipStream_t stream) {
    (void)hipMemsetAsync(d_out, 0, sizeof(float), stream);
    // 64 batch-groups (128 elems: 4 waves x 32) x 32 chunks = 2048 blocks
    // = 8 blocks/CU = 32 waves/CU launched; VGPR ~52 (<=64) so HW grants all 8
    // waves/SIMD without the spill-inducing (256,8) allocator cap.
    gru_nll_kernel<<<2048, 256, 0, stream>>>(
        (const int*)d_in[0],
        (const float*)d_in[1],  (const float*)d_in[2],
        (const float*)d_in[3],  (const float*)d_in[4],
        (const float*)d_in[5],  (const float*)d_in[6],
        (const float*)d_in[7],  (const float*)d_in[8],
        (const float*)d_in[9],  (const float*)d_in[10],
        (const float*)d_in[11], (const float*)d_in[12],
        (const float*)d_in[13], (const float*)d_in[14],
        (float*)d_out);
}